// Round 2
// baseline (492.939 us; speedup 1.0000x reference)
//
#include <hip/hip_runtime.h>
#include <stdint.h>

typedef unsigned int   u32;
typedef unsigned short u16;
typedef u32   u32x4 __attribute__((ext_vector_type(4)));
typedef float f32x4 __attribute__((ext_vector_type(4)));
typedef u16   u16x4 __attribute__((ext_vector_type(4)));

// fp32 -> bf16 round-to-nearest-even
__device__ __forceinline__ u16 f2bf(float f) {
  u32 u = __float_as_uint(f);
  u32 r = (u + 0x7FFFu + ((u >> 16) & 1u)) >> 16;
  return (u16)r;
}
__device__ __forceinline__ float bf2f(u16 h) {
  return __uint_as_float(((u32)h) << 16);
}
// D = A(16x32) * B(32x16) + D, bf16 in, f32 acc.
// A-frag: lane holds row (l&15), k = (l>>4)*8 + e (8 contiguous bf16 = 16B)
// B-frag: lane holds col (l&15), k = (l>>4)*8 + e
// D-frag: lane holds col (l&15), rows (l>>4)*4 + r
__device__ __forceinline__ void mfma_bf16(f32x4& acc, u32x4 a, u32x4 b) {
  asm("v_mfma_f32_16x16x32_bf16 %0, %1, %2, %0" : "+v"(acc) : "v"(a), "v"(b));
}

// ---------------- fp32 -> bf16 convert ----------------
__global__ void __launch_bounds__(256) k_convert(const float* __restrict__ in,
                                                 u16* __restrict__ out, int n4) {
  int i = blockIdx.x * 256 + threadIdx.x;
  int stride = gridDim.x * 256;
  for (; i < n4; i += stride) {
    f32x4 v = *(const f32x4*)(in + (size_t)i * 4);
    u16x4 o;
    o.x = f2bf(v.x); o.y = f2bf(v.y); o.z = f2bf(v.z); o.w = f2bf(v.w);
    *(u16x4*)(out + (size_t)i * 4) = o;
  }
}

// ---------------- GEMM: C[M][N] = A[M][K] * Bw[N][K]^T (+bias) ----------------
// 128x128 tile, BK=64, 4 waves (each 64x64), padded LDS (stride 72 elems).
template <int OUT_BF16, int ADD_BIAS>
__global__ void __launch_bounds__(256) k_gemm_bt(const u16* __restrict__ A,
                                                 const u16* __restrict__ Bw,
                                                 void* __restrict__ Cout,
                                                 const float* __restrict__ bias,
                                                 int M, int N, int K) {
  __shared__ __align__(16) u16 Al[128 * 72];
  __shared__ __align__(16) u16 Bl[128 * 72];
  const int t = threadIdx.x;
  const int wave = t >> 6, lane = t & 63;
  const int g = lane >> 4, lc = lane & 15;
  const int m0 = blockIdx.y * 128, n0 = blockIdx.x * 128;
  const int wr = (wave >> 1) * 64, wc = (wave & 1) * 64;

  f32x4 acc[4][4] = {};
  const int nkt = K >> 6;

  u32x4 pa[4], pb[4];
#pragma unroll
  for (int i = 0; i < 4; ++i) {  // prefetch kt=0
    int c = t + i * 256, row = c >> 3, cc = c & 7;
    pa[i] = *(const u32x4*)(A + (size_t)(m0 + row) * K + cc * 8);
    pb[i] = *(const u32x4*)(Bw + (size_t)(n0 + row) * K + cc * 8);
  }
  for (int kt = 0; kt < nkt; ++kt) {
    __syncthreads();  // previous tile fully consumed
#pragma unroll
    for (int i = 0; i < 4; ++i) {
      int c = t + i * 256, row = c >> 3, cc = c & 7;
      *(u32x4*)(Al + row * 72 + cc * 8) = pa[i];
      *(u32x4*)(Bl + row * 72 + cc * 8) = pb[i];
    }
    if (kt + 1 < nkt) {
      int k0 = (kt + 1) * 64;
#pragma unroll
      for (int i = 0; i < 4; ++i) {
        int c = t + i * 256, row = c >> 3, cc = c & 7;
        pa[i] = *(const u32x4*)(A + (size_t)(m0 + row) * K + k0 + cc * 8);
        pb[i] = *(const u32x4*)(Bw + (size_t)(n0 + row) * K + k0 + cc * 8);
      }
    }
    __syncthreads();  // tile ready
#pragma unroll
    for (int kk = 0; kk < 2; ++kk) {
      u32x4 af[4], bf[4];
#pragma unroll
      for (int mi = 0; mi < 4; ++mi)
        af[mi] = *(const u32x4*)(Al + (wr + mi * 16 + lc) * 72 + kk * 32 + g * 8);
#pragma unroll
      for (int ni = 0; ni < 4; ++ni)
        bf[ni] = *(const u32x4*)(Bl + (wc + ni * 16 + lc) * 72 + kk * 32 + g * 8);
#pragma unroll
      for (int mi = 0; mi < 4; ++mi)
#pragma unroll
        for (int ni = 0; ni < 4; ++ni)
          mfma_bf16(acc[mi][ni], af[mi], bf[ni]);
    }
  }
#pragma unroll
  for (int mi = 0; mi < 4; ++mi) {
#pragma unroll
    for (int ni = 0; ni < 4; ++ni) {
      int colg = n0 + wc + ni * 16 + lc;
      float bv = ADD_BIAS ? bias[colg] : 0.0f;
#pragma unroll
      for (int r = 0; r < 4; ++r) {
        int rowg = m0 + wr + mi * 16 + g * 4 + r;
        float v = acc[mi][ni][r] + bv;
        if (OUT_BF16) ((u16*)Cout)[(size_t)rowg * N + colg] = f2bf(v);
        else          ((float*)Cout)[(size_t)rowg * N + colg] = v;
      }
    }
  }
}

// ---------------- RMSNorm + RoPE for q,k;  [BN][6144]bf16 -> [B*H][N][D]bf16 --------
__global__ void __launch_bounds__(256) k_fuse_qk(const u16* __restrict__ qkv,
                                                 const float* __restrict__ cosb,
                                                 const float* __restrict__ sinb,
                                                 const float* __restrict__ qw,
                                                 const float* __restrict__ kw,
                                                 u16* __restrict__ qout,
                                                 u16* __restrict__ kout) {
  int row = blockIdx.x;  // 0..4095 = b*2048+n
  int b = row >> 11, n = row & 2047;
  int t = threadIdx.x, wave = t >> 6, lane = t & 63;
  int slot = wave & 1;  // 0=q, 1=k
  const float* nw = slot ? kw : qw;
  u16* outp = slot ? kout : qout;
  int d1 = lane, d2 = lane + 64;
  float c1 = cosb[n * 128 + d1], c2 = cosb[n * 128 + d2];
  float s1 = sinb[n * 128 + d1], s2 = sinb[n * 128 + d2];
  float w1 = nw[d1], w2 = nw[d2];
  const u16* base = qkv + (size_t)row * 6144 + slot * 2048;
#pragma unroll
  for (int i = 0; i < 8; ++i) {
    int h = (wave >> 1) * 8 + i;
    float x1 = bf2f(base[h * 128 + d1]);
    float x2 = bf2f(base[h * 128 + d2]);
    float ss = x1 * x1 + x2 * x2;
#pragma unroll
    for (int off = 32; off; off >>= 1) ss += __shfl_xor(ss, off);
    float rinv = rsqrtf(ss * (1.0f / 128.0f) + 1e-6f);
    float q1 = x1 * rinv * w1, q2 = x2 * rinv * w2;
    float o1 = q1 * c1 - q2 * s1;   // d < 64:  t*cos - t[d+64]*sin
    float o2 = q2 * c2 + q1 * s2;   // d >= 64: t*cos + t[d-64]*sin
    u16* op = outp + ((size_t)(b * 16 + h) * 2048 + n) * 128;
    op[d1] = f2bf(o1);
    op[d2] = f2bf(o2);
  }
}

// ---------------- V transpose: [BN][6144] slot2 -> Vt[B*H][D][N] ----------------
__global__ void __launch_bounds__(256) k_vt(const u16* __restrict__ qkv,
                                            u16* __restrict__ vt) {
  __shared__ __align__(16) u16 vl[64 * 136];
  int bh = blockIdx.x;         // 0..31
  int n0 = blockIdx.y * 64;    // n tile
  int b = bh >> 4, h = bh & 15;
  int t = threadIdx.x;
#pragma unroll
  for (int i = 0; i < 4; ++i) {
    int c = t + i * 256, j = c >> 4, cc = c & 15;
    u32x4 v = *(const u32x4*)(qkv + (size_t)(b * 2048 + n0 + j) * 6144 + 4096 + h * 128 + cc * 8);
    *(u32x4*)(vl + j * 136 + cc * 8) = v;
  }
  __syncthreads();
  int lane = t & 63, wave = t >> 6;
  int jj = (lane & 31) * 2;
#pragma unroll
  for (int it = 0; it < 16; ++it) {
    int d = it * 8 + wave * 2 + (lane >> 5);
    u32 lo = vl[jj * 136 + d];
    u32 hi = vl[(jj + 1) * 136 + d];
    *(u32*)(vt + ((size_t)bh * 128 + d) * 2048 + n0 + jj) = lo | (hi << 16);
  }
}

// ---------------- Flash attention: Q,K [BH][N][D], Vt [BH][D][N] -> aout [BN][2048] ---
__global__ void __launch_bounds__(256) k_attn(const u16* __restrict__ q,
                                              const u16* __restrict__ k,
                                              const u16* __restrict__ vt,
                                              u16* __restrict__ aout) {
  __shared__ __align__(16) u16 Kl[64 * 136];   // [key][d], padded
  __shared__ __align__(16) u16 Vl[128 * 72];   // [d][key], padded
  __shared__ __align__(16) u16 Pl[4][16 * 72]; // per-wave P [q][key], padded
  int bid = blockIdx.x;
  int bh = bid >> 5, qt = bid & 31;
  int t = threadIdx.x, wave = t >> 6, lane = t & 63;
  int g = lane >> 4, lc = lane & 15;
  int q0 = qt * 64 + wave * 16;
  const u16* qbase = q + (size_t)bh * 2048 * 128;
  const u16* kbase = k + (size_t)bh * 2048 * 128;
  const u16* vbase = vt + (size_t)bh * 128 * 2048;

  u32x4 qf[4];
#pragma unroll
  for (int s = 0; s < 4; ++s)
    qf[s] = *(const u32x4*)(qbase + (size_t)(q0 + lc) * 128 + s * 32 + g * 8);

  f32x4 o[8] = {};
  float mrow[4], lrow[4];
#pragma unroll
  for (int r = 0; r < 4; ++r) { mrow[r] = -1e30f; lrow[r] = 0.0f; }
  const float scale = 0.08838834764831845f;  // 1/sqrt(128)

  u32x4 sk[4], sv[4];
#pragma unroll
  for (int i = 0; i < 4; ++i) {  // prefetch kt=0
    int c = t + i * 256;
    { int row = c >> 4, cc = c & 15;
      sk[i] = *(const u32x4*)(kbase + (size_t)row * 128 + cc * 8); }
    { int row = c >> 3, cc = c & 7;
      sv[i] = *(const u32x4*)(vbase + (size_t)row * 2048 + cc * 8); }
  }
  for (int kt = 0; kt < 32; ++kt) {
    __syncthreads();
#pragma unroll
    for (int i = 0; i < 4; ++i) {
      int c = t + i * 256;
      { int row = c >> 4, cc = c & 15; *(u32x4*)(Kl + row * 136 + cc * 8) = sk[i]; }
      { int row = c >> 3, cc = c & 7;  *(u32x4*)(Vl + row * 72 + cc * 8)  = sv[i]; }
    }
    if (kt + 1 < 32) {
      int kn = (kt + 1) * 64;
#pragma unroll
      for (int i = 0; i < 4; ++i) {
        int c = t + i * 256;
        { int row = c >> 4, cc = c & 15;
          sk[i] = *(const u32x4*)(kbase + (size_t)(kn + row) * 128 + cc * 8); }
        { int row = c >> 3, cc = c & 7;
          sv[i] = *(const u32x4*)(vbase + (size_t)row * 2048 + kn + cc * 8); }
      }
    }
    __syncthreads();
    // S = Q K^T (this 64-key tile), 16 q-rows per wave
    f32x4 s[4] = {};
#pragma unroll
    for (int kb = 0; kb < 4; ++kb) {
#pragma unroll
      for (int ds = 0; ds < 4; ++ds) {
        u32x4 kf = *(const u32x4*)(Kl + (kb * 16 + lc) * 136 + ds * 32 + g * 8);
        mfma_bf16(s[kb], qf[ds], kf);
      }
    }
#pragma unroll
    for (int kb = 0; kb < 4; ++kb) s[kb] *= scale;
    // online softmax (wave-parallel, rows live in (g, r))
    float alpha[4];
#pragma unroll
    for (int r = 0; r < 4; ++r) {
      float mm = fmaxf(fmaxf(s[0][r], s[1][r]), fmaxf(s[2][r], s[3][r]));
#pragma unroll
      for (int off = 8; off; off >>= 1) mm = fmaxf(mm, __shfl_xor(mm, off));
      float mnew = fmaxf(mrow[r], mm);
      alpha[r] = __expf(mrow[r] - mnew);
      float rs = 0.0f;
#pragma unroll
      for (int kb = 0; kb < 4; ++kb) {
        float p = __expf(s[kb][r] - mnew);
        s[kb][r] = p;
        rs += p;
      }
#pragma unroll
      for (int off = 8; off; off >>= 1) rs += __shfl_xor(rs, off);
      lrow[r] = lrow[r] * alpha[r] + rs;
      mrow[r] = mnew;
    }
#pragma unroll
    for (int df = 0; df < 8; ++df)
#pragma unroll
      for (int r = 0; r < 4; ++r) o[df][r] *= alpha[r];
    // P -> per-wave LDS (C-layout -> A-layout fix-up)
    u16* pw = &Pl[wave][0];
#pragma unroll
    for (int kb = 0; kb < 4; ++kb)
#pragma unroll
      for (int r = 0; r < 4; ++r)
        pw[(g * 4 + r) * 72 + kb * 16 + lc] = f2bf(s[kb][r]);
    // O += P V
#pragma unroll
    for (int kb2 = 0; kb2 < 2; ++kb2) {
      u32x4 pf = *(const u32x4*)(pw + lc * 72 + kb2 * 32 + g * 8);
#pragma unroll
      for (int df = 0; df < 8; ++df) {
        u32x4 vf = *(const u32x4*)(Vl + (df * 16 + lc) * 72 + kb2 * 32 + g * 8);
        mfma_bf16(o[df], pf, vf);
      }
    }
  }
  // epilogue: out[b, n, h*128 + d]
  int b = bh >> 4, h = bh & 15;
#pragma unroll
  for (int df = 0; df < 8; ++df) {
#pragma unroll
    for (int r = 0; r < 4; ++r) {
      float vv = o[df][r] / lrow[r];
      int rowg = b * 2048 + q0 + g * 4 + r;
      int colg = h * 128 + df * 16 + lc;
      aout[(size_t)rowg * 2048 + colg] = f2bf(vv);
    }
  }
}

extern "C" void kernel_launch(void* const* d_in, const int* in_sizes, int n_in,
                              void* d_out, int out_size, void* d_ws, size_t ws_size,
                              hipStream_t stream) {
  const float* x        = (const float*)d_in[0];
  const float* rope_cos = (const float*)d_in[1];
  const float* rope_sin = (const float*)d_in[2];
  const float* qkv_w    = (const float*)d_in[3];
  const float* proj_w   = (const float*)d_in[4];
  const float* proj_b   = (const float*)d_in[5];
  const float* q_norm_w = (const float*)d_in[6];
  const float* k_norm_w = (const float*)d_in[7];
  (void)in_sizes; (void)n_in; (void)out_size; (void)ws_size;

  // workspace layout (bytes), total 128 MB with reuse:
  //   [0,16M)      xbf   (x as bf16)          -> reused as qh after GEMM1
  //   [16M,41.9M)  wbf   (qkv_w bf16)         -> first 16.7M reused as aout
  //   [41.9M,50.3M) pwbf (proj_w bf16)
  //   [50.3M,100.7M) qkvbf (GEMM1 out, bf16)
  //   [100.7M,117.4M) kh
  //   [117.4M,134.2M) vth
  char* ws = (char*)d_ws;
  u16* xbf   = (u16*)(ws);
  u16* wbf   = (u16*)(ws + 16777216);
  u16* pwbf  = (u16*)(ws + 41943040);
  u16* qkvbf = (u16*)(ws + 50331648);
  u16* qh    = (u16*)(ws);             // overlays xbf (x dead after GEMM1)
  u16* kh    = (u16*)(ws + 100663296);
  u16* vth   = (u16*)(ws + 117440512);
  u16* aoutb = (u16*)(ws + 16777216);  // overlays wbf (dead after GEMM1)
  float* out = (float*)d_out;

  k_convert<<<2048, 256, 0, stream>>>(x, xbf, 2097152);
  k_convert<<<2048, 256, 0, stream>>>(qkv_w, wbf, 3145728);
  k_convert<<<2048, 256, 0, stream>>>(proj_w, pwbf, 1048576);
  k_gemm_bt<1, 0><<<dim3(48, 32), 256, 0, stream>>>(xbf, wbf, qkvbf, nullptr,
                                                    4096, 6144, 2048);
  k_fuse_qk<<<4096, 256, 0, stream>>>(qkvbf, rope_cos, rope_sin, q_norm_w,
                                      k_norm_w, qh, kh);
  k_vt<<<dim3(32, 32), 256, 0, stream>>>(qkvbf, vth);
  k_attn<<<1024, 256, 0, stream>>>(qh, kh, vth, aoutb);
  k_gemm_bt<0, 1><<<dim3(16, 32), 256, 0, stream>>>(aoutb, pwbf, out, proj_b,
                                                    4096, 2048, 2048);
}